// Round 14
// baseline (393.323 us; speedup 1.0000x reference)
//
#include <hip/hip_runtime.h>
#include <math.h>

#define IN_DIM 768
#define HID    1024
#define OUTD   18
#define BATCH  16
#define PERTSZ 64
#define IMH    512
#define IMW    512
#define LN_EPS 1e-5f

// Video (16,3,2,512,512) fp32. Per (b,ch): 2 frames x 65536 float4.
#define SLICE4   65536
#define PAIR4    131072
#define NB1      512
#define F0TOTAL4 3145728L   // 48 slices * 65536 float4

// ---------------------------------------------------------------------------
// Device-scope grid barrier (all NB1 blocks co-resident: 512 blocks, 2/CU).
// Release: __syncthreads (drains this block's stores) + thread0 __threadfence
// (L2 writeback to device coherence point). Acquire: polled device-scope
// atomic load + __threadfence (L1/L2 invalidate) + __syncthreads.
// ---------------------------------------------------------------------------
__device__ __forceinline__ void grid_barrier(unsigned* bar, unsigned nb)
{
    __syncthreads();
    if (threadIdx.x == 0) {
        __threadfence();
        atomicAdd(bar, 1u);   // device scope by default on global
        while (__hip_atomic_load(bar, __ATOMIC_RELAXED, __HIP_MEMORY_SCOPE_AGENT) < nb)
            __builtin_amdgcn_s_sleep(2);
        __threadfence();
    }
    __syncthreads();
}

// ---------------------------------------------------------------------------
// Copy [lo,hi) of the virtual per-frame float4 stream (48 slices x 65536).
// frameOff4 = 0 (frame 0) or SLICE4 (frame 1). Pool = blocks [poolStart, ...).
// ---------------------------------------------------------------------------
__device__ __forceinline__ void copy_frame_range(const float4* __restrict__ src,
                                                 float4* __restrict__ dst,
                                                 long lo, long hi,
                                                 int poolStart, int poolSize,
                                                 int frameOff4)
{
    for (long v = lo + (long)(blockIdx.x - poolStart) * blockDim.x + threadIdx.x;
         v < hi; v += (long)poolSize * blockDim.x) {
        const long s   = v >> 16;
        const long off = v & (SLICE4 - 1);
        const size_t i4 = (size_t)s * PAIR4 + frameOff4 + off;
        dst[i4] = src[i4];
    }
}

// ---------------------------------------------------------------------------
// One GEMM phase on blocks 0..255: y[b][col] = bias[col] + dot(x[b,:],W[:,col]).
// b = blk>>4, colblock = blk&15 (64 cols). 256 thr = 64 cols x 4 K-slices;
// W reads are 256B coalesced rows. LDS reduce of 4 partials.
// ---------------------------------------------------------------------------
__device__ __forceinline__ void gemm_block(const float* __restrict__ x,
                                           const float* __restrict__ W,
                                           const float* __restrict__ bias,
                                           float* __restrict__ y,
                                           int K, int N, float* xs, float* red)
{
    const int b  = blockIdx.x >> 4;
    const int cb = blockIdx.x & 15;
    const int t  = threadIdx.x;
    const int k4 = K >> 2;                   // float4 count per row (192/256)
    if (t < k4) ((float4*)xs)[t] = ((const float4*)x)[(size_t)b * k4 + t];
    __syncthreads();

    const int col    = cb * 64 + (t & 63);
    const int kchunk = K >> 2;               // 192 or 256, %8==0
    const int k0     = (t >> 6) * kchunk;
    float acc = 0.f;
    #pragma unroll 8
    for (int k = 0; k < kchunk; ++k)
        acc += xs[k0 + k] * W[(size_t)(k0 + k) * N + col];
    red[t] = acc;
    __syncthreads();

    if (t < 64) {
        const float s = red[t] + red[t + 64] + red[t + 128] + red[t + 192];
        y[(size_t)b * N + cb * 64 + t] = s + bias[cb * 64 + t];
    }
    __syncthreads();   // xs/red reused next phase
}

// ---------------------------------------------------------------------------
// LayerNorm(1024)+ReLU on blocks 0..15 (b = blockIdx.x).
// ---------------------------------------------------------------------------
__device__ __forceinline__ void ln_block(const float* __restrict__ y,
                                         const float* __restrict__ g,
                                         const float* __restrict__ be,
                                         float* __restrict__ x, float* red4)
{
    const int b = blockIdx.x;
    const int t = threadIdx.x;
    const float* yr = y + b * HID;
    float v[4];
    #pragma unroll
    for (int i = 0; i < 4; ++i) v[i] = yr[t + i * 256];

    float s = v[0] + v[1] + v[2] + v[3];
    #pragma unroll
    for (int o = 32; o > 0; o >>= 1) s += __shfl_down(s, o, 64);
    const int wid = t >> 6, lane = t & 63;
    if (lane == 0) red4[wid] = s;
    __syncthreads();
    const float m = (red4[0] + red4[1] + red4[2] + red4[3]) * (1.0f / HID);

    float sq = 0.f;
    #pragma unroll
    for (int i = 0; i < 4; ++i) { float d = v[i] - m; sq += d * d; }
    __syncthreads();
    #pragma unroll
    for (int o = 32; o > 0; o >>= 1) sq += __shfl_down(sq, o, 64);
    if (lane == 0) red4[wid] = sq;
    __syncthreads();
    const float var = (red4[0] + red4[1] + red4[2] + red4[3]) * (1.0f / HID);
    const float rstd = rsqrtf(var + LN_EPS);

    #pragma unroll
    for (int i = 0; i < 4; ++i) {
        const int j = t + i * 256;
        float o_ = (v[i] - m) * rstd * g[j] + be[j];
        x[b * HID + j] = fmaxf(o_, 0.0f);
    }
    __syncthreads();
}

// ---------------------------------------------------------------------------
// K1: GEMM1 | LN1 | GEMM2 | LN2 with grid barriers; 256 copy blocks stream
// frame-0 through all phases (pool widens to 496 during LN phases).
// ---------------------------------------------------------------------------
__global__ __launch_bounds__(256, 2) void mlp_f0_kernel(
    const float* __restrict__ enc,
    const float* __restrict__ W1, const float* __restrict__ b1,
    const float* __restrict__ g1, const float* __restrict__ be1,
    const float* __restrict__ W2, const float* __restrict__ b2,
    const float* __restrict__ g2, const float* __restrict__ be2,
    float* y1, float* x1, float* y2, float* x2, unsigned* bar,
    const float4* __restrict__ v4, float4* __restrict__ o4)
{
    __shared__ float xs[1024];
    __shared__ float red[256];
    const int blk = blockIdx.x;

    // Phase A: GEMM1 + copy f0[0, 1081344)
    if (blk < 256) gemm_block(enc, W1, b1, y1, IN_DIM, HID, xs, red);
    else           copy_frame_range(v4, o4, 0L, 1081344L, 256, 256, 0);
    grid_barrier(bar + 0, NB1);

    // Phase B: LN1 + copy f0[1081344, 1572864)
    if (blk < 16)  ln_block(y1, g1, be1, x1, red);
    else           copy_frame_range(v4, o4, 1081344L, 1572864L, 16, 496, 0);
    grid_barrier(bar + 16, NB1);

    // Phase C: GEMM2 + copy f0[1572864, 2654208)
    if (blk < 256) gemm_block(x1, W2, b2, y2, HID, HID, xs, red);
    else           copy_frame_range(v4, o4, 1572864L, 2654208L, 256, 256, 0);
    grid_barrier(bar + 32, NB1);

    // Phase D: LN2 + copy f0[2654208, end)
    if (blk < 16)  ln_block(y2, g2, be2, x2, red);
    else           copy_frame_range(v4, o4, 2654208L, F0TOTAL4, 16, 496, 0);
}

// ---------------------------------------------------------------------------
// K2: 16 blocks: GEMM3(K=1024->18)+LN(18)+tanh+patch+scatter (frame 0);
// 2032 blocks copy frame-1. pert = amp*exp(-0.5*(quad-min quad)).
// ---------------------------------------------------------------------------
__global__ __launch_bounds__(256) void final_f1_kernel(
    const float* __restrict__ x2, const float* __restrict__ W3,
    const float* __restrict__ b3, const float* __restrict__ g3,
    const float* __restrict__ be3, const int* __restrict__ loc,
    float* __restrict__ out,
    const float4* __restrict__ v4, float4* __restrict__ o4)
{
    if ((int)blockIdx.x >= 16) {
        copy_frame_range(v4, o4, 0L, F0TOTAL4, 16, 2032, SLICE4);
        return;
    }
    __shared__ float xs[HID];
    __shared__ float y3[OUTD];
    __shared__ float mv[2];
    __shared__ float red[4];
    const int b = blockIdx.x;
    const int t = threadIdx.x;
    for (int k = t; k < HID; k += 256) xs[k] = x2[b * HID + k];
    __syncthreads();

    if (t < 64) {
        float local[OUTD];
        #pragma unroll
        for (int j = 0; j < OUTD; ++j) local[j] = 0.f;
        const float* xk = xs + t * 16;
        const float* wk = W3 + t * 16 * OUTD;
        #pragma unroll 4
        for (int kk = 0; kk < 16; ++kk) {
            const float xv = xk[kk];
            #pragma unroll
            for (int j = 0; j < OUTD; ++j) local[j] += xv * wk[kk * OUTD + j];
        }
        #pragma unroll
        for (int j = 0; j < OUTD; ++j) {
            #pragma unroll
            for (int o = 32; o > 0; o >>= 1) local[j] += __shfl_xor(local[j], o, 64);
        }
        if (t < OUTD) y3[t] = local[t] + b3[t];
    }
    __syncthreads();

    if (t == 0) {
        float s = 0.f;
        for (int j = 0; j < OUTD; ++j) s += y3[j];
        const float m = s * (1.0f / OUTD);
        float sq = 0.f;
        for (int j = 0; j < OUTD; ++j) { float d = y3[j] - m; sq += d * d; }
        mv[0] = m;
        mv[1] = rsqrtf(sq * (1.0f / OUTD) + LN_EPS);
    }
    __syncthreads();
    if (t < OUTD) {
        const float tv = (y3[t] - mv[0]) * mv[1] * g3[t] + be3[t];
        y3[t] = tanhf(tv);
    }
    __syncthreads();

    const int r0 = loc[b * 2 + 0] - PERTSZ / 2;
    const int c0 = loc[b * 2 + 1] - PERTSZ / 2;
    const int wid = t >> 6, lane = t & 63;
    const float step = 64.0f / 63.0f;

    for (int ch = 0; ch < 3; ++ch) {
        const float* p = &y3[ch * 6];
        const float mean0 = p[0] * 32.0f;
        const float mean1 = p[1] * 32.0f;
        const float rs_ = (p[2] + 1.0f) * 15.5f + 1.0f;
        const float cs_ = (p[3] + 1.0f) * 15.5f + 1.0f;
        const float corr = p[4] * 0.98f;
        const float amp  = p[5];
        const float det = (rs_ * cs_) * (rs_ * cs_) * (1.0f - corr * corr);
        const float i00 = cs_ * cs_ / det;
        const float i11 = rs_ * rs_ / det;
        const float i01 = -(rs_ * cs_ * corr) / det;

        float q[16];
        float qmin = 1e30f;
        #pragma unroll
        for (int tt = 0; tt < 16; ++tt) {
            const int idx = t + tt * 256;
            const int i = idx >> 6, j = idx & 63;
            const float d0 = (-32.0f + i * step) - mean0;
            const float d1 = (-32.0f + j * step) - mean1;
            const float quad = i00 * d0 * d0 + 2.0f * i01 * d0 * d1 + i11 * d1 * d1;
            q[tt] = quad;
            qmin = fminf(qmin, quad);
        }
        #pragma unroll
        for (int o = 32; o > 0; o >>= 1) qmin = fminf(qmin, __shfl_xor(qmin, o, 64));
        if (lane == 0) red[wid] = qmin;
        __syncthreads();
        const float qm = fminf(fminf(red[0], red[1]), fminf(red[2], red[3]));

        float* base = out + ((size_t)(b * 3 + ch) * 2) * (IMH * IMW);
        #pragma unroll
        for (int tt = 0; tt < 16; ++tt) {
            const int idx = t + tt * 256;
            const int i = idx >> 6, j = idx & 63;
            const int r = r0 + i, c = c0 + j;
            if ((unsigned)r < (unsigned)IMH && (unsigned)c < (unsigned)IMW)
                base[(size_t)r * IMW + c] += amp * expf(-0.5f * (q[tt] - qm));
        }
        __syncthreads();
    }
}

// ---------------------------------------------------------------------------
extern "C" void kernel_launch(void* const* d_in, const int* in_sizes, int n_in,
                              void* d_out, int out_size, void* d_ws, size_t ws_size,
                              hipStream_t stream)
{
    const float* video = (const float*)d_in[0];
    const float* enc   = (const float*)d_in[1];
    const int*   loc   = (const int*)  d_in[2];
    const float* W1 = (const float*)d_in[3];
    const float* b1 = (const float*)d_in[4];
    const float* g1 = (const float*)d_in[5];
    const float* be1= (const float*)d_in[6];
    const float* W2 = (const float*)d_in[7];
    const float* b2 = (const float*)d_in[8];
    const float* g2 = (const float*)d_in[9];
    const float* be2= (const float*)d_in[10];
    const float* W3 = (const float*)d_in[11];
    const float* b3 = (const float*)d_in[12];
    const float* g3 = (const float*)d_in[13];
    const float* be3= (const float*)d_in[14];
    float* out = (float*)d_out;

    float* ws = (float*)d_ws;
    float* y1 = ws;              // 16*1024
    float* x1 = ws + 16384;
    float* y2 = ws + 32768;
    float* x2 = ws + 49152;
    unsigned* bar = (unsigned*)(ws + 65536);   // 3 counters, 64B apart

    const float4* v4 = (const float4*)video;
    float4*       o4 = (float4*)out;

    hipMemsetAsync(bar, 0, 256, stream);
    mlp_f0_kernel<<<NB1, 256, 0, stream>>>(enc, W1, b1, g1, be1,
                                           W2, b2, g2, be2,
                                           y1, x1, y2, x2, bar, v4, o4);
    final_f1_kernel<<<2048, 256, 0, stream>>>(x2, W3, b3, g3, be3, loc, out,
                                              v4, o4);
}